// Round 23
// baseline (200.434 us; speedup 1.0000x reference)
//
#include <hip/hip_runtime.h>
#include <math.h>

typedef short short8 __attribute__((ext_vector_type(8)));
typedef float f32x4 __attribute__((ext_vector_type(4)));
typedef float f32x2 __attribute__((ext_vector_type(2)));

#define WP 132    // wtile pitch (f32)
#define OP 136    // otile pitch (bf16)
#define SC_C 8192 // k_scat2 chunk (edges)
#define SC_NB 832 // k_scat2 max tile-bins per bucket (<=783 for N=100000)
#define GCAP 1024 // k_gather3 LDS pair capacity
#define DG_SUB 16 // k_deg3 node-subranges per bucket
#define DG_LCAP 1024 // >= ceil(ceil(131072/8)/16); packing bounds N<=131072

// fp8 (e4m3) storage for the g table via gfx950 HW cvt; bf16 fallback.
#if defined(__has_builtin)
#if __has_builtin(__builtin_amdgcn_cvt_pk_f32_fp8) && \
    __has_builtin(__builtin_amdgcn_cvt_pk_fp8_f32)
#define GFP8 1
#endif
#endif
#ifndef GFP8
#define GFP8 0
#endif

// Packing (valid for N <= 131072): sp1 = (src<<14) | (d - bucket_lo),
// sp2 = (src<<4) | (d & 15).  sp2 is grouped by 16-node tile.
// sp1 buckets are capacity-padded regions: bucket b at [b*CAP, b*CAP+bcur[b*16]).

__device__ __forceinline__ short f2bf(float x) {
    unsigned u = __float_as_uint(x);
    u += 0x7fffu + ((u >> 16) & 1u);
    return (short)(u >> 16);
}

// ---------------------------------------------------------------------------
// Single-pass partition (replaces count+scan+scatter): each wave owns a
// contiguous edge window; pass1 counts 8 buckets in registers (ballot);
// block LDS-combine + ONE global atomic per bucket per block reserves space;
// pass2 re-reads the window (L2-hot) and writes packed pairs. Order within a
// bucket is non-deterministic across runs, but all consumers are
// order-insensitive (histograms / float sums within threshold).
// Blocks >= PBLK do the weight-table transform (k_tabs folded in).
__global__ void k_part_tabs(const int* __restrict__ src, const int* __restrict__ dst,
                            int* __restrict__ bcur, unsigned* __restrict__ sp1,
                            const float* __restrict__ emb,
                            const float* __restrict__ W1,
                            const float* __restrict__ W2,
                            short* __restrict__ T1T, short* __restrict__ W2T,
                            int E, int N, int PBLK, int CAP) {
    if (blockIdx.x >= PBLK) {                  // tabs part (block-uniform branch)
        int id = (blockIdx.x - PBLK) * 256 + threadIdx.x;
        if (id < 128 * 128) {
            int f = id >> 7, c = id & 127;
            float acc = 0.f;
#pragma unroll
            for (int k = 0; k < 64; ++k) acc += emb[c * 64 + k] * W1[k * 128 + f];
            T1T[id] = f2bf(acc);
        } else {
            int id2 = id - 128 * 128;
            if (id2 < 64 * 128) {
                int f = id2 >> 7, k = id2 & 127;
                W2T[id2] = f2bf(W2[k * 64 + f]);
            }
        }
        return;
    }
    __shared__ int wcnts[4][8];
    __shared__ int gbase[8];
    int tid = threadIdx.x, w = tid >> 6, lane = tid & 63;
    int CHB = (E + PBLK - 1) / PBLK;
    int CHW = (CHB + 3) / 4;
    int bbeg = blockIdx.x * CHB;
    int bend = min(bbeg + CHB, E);
    int wbeg = min(bbeg + w * CHW, bend);
    int wend = min(wbeg + CHW, bend);

    // pass 1: register bucket counts over the wave's window
    int cnt[8] = {0, 0, 0, 0, 0, 0, 0, 0};
    for (int base = wbeg; base < wend; base += 64) {
        int i = base + lane;
        bool valid = (i < wend);
        int d = valid ? dst[i] : 0;
        int b = valid ? (int)(((long long)d * 8) / N) : -1;
#pragma unroll
        for (int k = 0; k < 8; ++k)
            cnt[k] += (int)__popcll(__ballot(b == k));
    }
    if (lane == 0) {
#pragma unroll
        for (int k = 0; k < 8; ++k) wcnts[w][k] = cnt[k];
    }
    __syncthreads();
    if (tid < 8) {
        int tot = wcnts[0][tid] + wcnts[1][tid] + wcnts[2][tid] + wcnts[3][tid];
        gbase[tid] = (tot > 0) ? atomicAdd(&bcur[tid * 16], tot) : 0;
    }
    __syncthreads();
    int wb[8];
#pragma unroll
    for (int k = 0; k < 8; ++k) {
        int off = gbase[k];
        if (w > 0) off += wcnts[0][k];
        if (w > 1) off += wcnts[1][k];
        if (w > 2) off += wcnts[2][k];
        wb[k] = off;
    }
    // pass 2: re-read (L2-hot) and write packed pairs at reserved offsets
    for (int base = wbeg; base < wend; base += 64) {
        int i = base + lane;
        bool valid = (i < wend);
        int d = 0, s = 0;
        if (valid) { d = dst[i]; s = src[i]; }
        int b = valid ? (int)(((long long)d * 8) / N) : -1;
        unsigned packed = 0;
        if (valid) {
            int lo = (int)((long long)N * b / 8);
            packed = ((unsigned)s << 14) | (unsigned)(d - lo);
        }
#pragma unroll
        for (int k = 0; k < 8; ++k) {
            unsigned long long mk = __ballot(b == k);
            if (b == k) {
                int pref = (int)__popcll(mk & ((1ull << lane) - 1ull));
                sp1[(size_t)k * CAP + wb[k] + pref] = packed;
            }
            wb[k] += (int)__popcll(mk);
        }
    }
}

// Degree histogram with ZERO global atomics (8 buckets x 16 subranges x 2
// halves; LDS histogram + plain coalesced stores; scan sums the halves).
__global__ __launch_bounds__(1024) void k_deg3(
        const unsigned* __restrict__ sp1, const int* __restrict__ bcur,
        int* __restrict__ degi2, int N, int CAP) {
    __shared__ int h[DG_LCAP];
    int b   = blockIdx.x & 7;
    int hf  = (blockIdx.x >> 3) & 1;
    int sb  = blockIdx.x >> 4;
    int tid = threadIdx.x;
    int lo = (int)((long long)N * b / 8);
    int hi = (int)((long long)N * (b + 1) / 8);
    int range = hi - lo;
    int sub = (range + DG_SUB - 1) / DG_SUB;
    int nlo = sb * sub;
    int nhi = min(nlo + sub, range);
    int cnt = nhi - nlo;
    if (cnt <= 0) return;                      // uniform across block
    for (int i = tid; i < cnt; i += 1024) h[i] = 0;
    __syncthreads();
    int span = bcur[b * 16];
    const unsigned* pb = sp1 + (size_t)b * CAP;
    int hb = hf * (span >> 1);
    int he = (hf == 0) ? (span >> 1) : span;
    for (int i = hb + tid; i < he; i += 1024) {
        int dl = (int)(pb[i] & 16383u) - nlo;
        if ((unsigned)dl < (unsigned)cnt) atomicAdd(&h[dl], 1);
    }
    __syncthreads();
    int* dout = degi2 + (size_t)hf * N + lo + nlo;
    for (int i = tid; i < cnt; i += 1024) dout[i] = h[i];
}

// Phase 3: bucket -> 16-node-tile groups with LDS-staged COALESCED writes.
__global__ __launch_bounds__(256) void k_scat2(
        const unsigned* __restrict__ sp1, const int* __restrict__ bcur,
        int* __restrict__ tcur, unsigned* __restrict__ sp2,
        int N, int CAP) {
    __shared__ unsigned staged[SC_C];
    __shared__ int hist[SC_NB], hstart[SC_NB], hoff[SC_NB], gbase[SC_NB];
    __shared__ int sdata[256];
    int b = blockIdx.x & 7;
    int nb = gridDim.x >> 3, bi = blockIdx.x >> 3;
    int lo = (int)((long long)N * b / 8);
    int t0 = lo >> 4;
    int end = bcur[b * 16];
    const unsigned* pb = sp1 + (size_t)b * CAP;
    int tid = threadIdx.x;

    for (int cb = bi * SC_C; cb < end; cb += nb * SC_C) {
        int count = min(SC_C, end - cb);
        for (int j = tid; j < SC_NB; j += 256) hist[j] = 0;
        __syncthreads();

        unsigned v[SC_C / 256];
#pragma unroll
        for (int j = 0; j < SC_C / 256; ++j) {
            int i = j * 256 + tid;
            v[j] = 0;
            if (i < count) {
                unsigned sp = pb[cb + i];
                v[j] = sp;
                atomicAdd(&hist[(int)(sp & 16383u) >> 4 << 0 ? ((int)((sp & 16383u)) + lo >> 4) - t0 : 0], 0);
            }
        }
        __syncthreads();
        // NOTE: the line above must not exist; histogram done below correctly.
        // (kept structure identical to proven version)
        for (int j = tid; j < SC_NB; j += 256) hist[j] = 0;
        __syncthreads();
#pragma unroll
        for (int j = 0; j < SC_C / 256; ++j) {
            int i = j * 256 + tid;
            if (i < count) {
                int d = (int)(v[j] & 16383u) + lo;
                atomicAdd(&hist[(d >> 4) - t0], 1);
            }
        }
        __syncthreads();

        int loc[4]; int lsum = 0;
#pragma unroll
        for (int j = 0; j < 4; ++j) {
            int idx = tid * 4 + j;
            loc[j] = (idx < SC_NB) ? hist[idx] : 0;
            lsum += loc[j];
        }
        sdata[tid] = lsum;
        __syncthreads();
        for (int off = 1; off < 256; off <<= 1) {
            int add = (tid >= off) ? sdata[tid - off] : 0;
            __syncthreads();
            sdata[tid] += add;
            __syncthreads();
        }
        int excl = sdata[tid] - lsum;
        int run = 0;
#pragma unroll
        for (int j = 0; j < 4; ++j) {
            int idx = tid * 4 + j;
            if (idx < SC_NB) { hstart[idx] = excl + run; hoff[idx] = excl + run; }
            run += loc[j];
        }
        __syncthreads();

        for (int j = tid; j < SC_NB; j += 256)
            if (hist[j] > 0) gbase[j] = atomicAdd(&tcur[t0 + j], hist[j]);
#pragma unroll
        for (int j = 0; j < SC_C / 256; ++j) {
            int i = j * 256 + tid;
            if (i < count) {
                int d = (int)(v[j] & 16383u) + lo;
                int bin = (d >> 4) - t0;
                int old = atomicAdd(&hoff[bin], 1);
                staged[old] = v[j];
            }
        }
        __syncthreads();

        for (int i = tid; i < count; i += 256) {
            unsigned sp = staged[i];
            int d = (int)(sp & 16383u) + lo;
            int bin = (d >> 4) - t0;
            int pos = gbase[bin] + (i - hstart[bin]);
            unsigned s = sp >> 14;
            sp2[pos] = (s << 4) | (unsigned)(d & 15);
        }
        __syncthreads();
    }
}

// ---------------------------------------------------------------------------
// Exclusive scans. in2 optional (summed); dis/ndpk optional; tail optional.
__global__ void k_scan_a(const int* __restrict__ in, const int* __restrict__ in2,
                         int* __restrict__ outp, int* __restrict__ csums,
                         float* __restrict__ dis, const int* __restrict__ nid,
                         int2* __restrict__ ndpk, int n) {
    __shared__ int sdata[256];
    int tid = threadIdx.x;
    int idx = blockIdx.x * 1024 + tid * 4;
    int v[4];
#pragma unroll
    for (int j = 0; j < 4; ++j) {
        v[j] = 0;
        if (idx + j < n) {
            v[j] = in[idx + j];
            if (in2 != nullptr) v[j] += in2[idx + j];
            if (dis != nullptr) {
                float dv = rsqrtf((float)(v[j] + 1));
                dis[idx + j] = dv;
                int2 nd; nd.x = nid[idx + j]; nd.y = __float_as_int(dv);
                ndpk[idx + j] = nd;
            }
        }
    }
    int tsum = v[0] + v[1] + v[2] + v[3];
    sdata[tid] = tsum;
    __syncthreads();
    for (int off = 1; off < 256; off <<= 1) {
        int add = (tid >= off) ? sdata[tid - off] : 0;
        __syncthreads();
        sdata[tid] += add;
        __syncthreads();
    }
    int excl = sdata[tid] - tsum;
    int run = 0;
#pragma unroll
    for (int j = 0; j < 4; ++j) {
        if (idx + j < n) outp[idx + j] = excl + run;
        run += v[j];
    }
    if (tid == 255) csums[blockIdx.x] = sdata[255];
}

__global__ void k_scan_b(int* __restrict__ csums, int nch) {
    __shared__ int sdata[256];
    int tid = threadIdx.x;
    int v[4];
#pragma unroll
    for (int j = 0; j < 4; ++j) {
        int i = tid * 4 + j;
        v[j] = (i < nch) ? csums[i] : 0;
    }
    int tsum = v[0] + v[1] + v[2] + v[3];
    sdata[tid] = tsum;
    __syncthreads();
    for (int off = 1; off < 256; off <<= 1) {
        int add = (tid >= off) ? sdata[tid - off] : 0;
        __syncthreads();
        sdata[tid] += add;
        __syncthreads();
    }
    int excl = sdata[tid] - tsum;
    int run = 0;
#pragma unroll
    for (int j = 0; j < 4; ++j) {
        int i = tid * 4 + j;
        if (i < nch) csums[i] = excl + run;
        run += v[j];
    }
}

// scan_c: add chunk offsets; optional rowptr tail; optional tcur side-output.
__global__ void k_scan_c(int* __restrict__ outp, const int* __restrict__ csums,
                         int n, int E, int writeTail, int* __restrict__ tcur) {
    int idx = blockIdx.x * 1024 + threadIdx.x * 4;
    int add = csums[blockIdx.x];
#pragma unroll
    for (int j = 0; j < 4; ++j) {
        int k = idx + j;
        if (k < n) {
            int r = outp[k] + add;
            outp[k] = r;
            if (tcur != nullptr && (k & 15) == 0) tcur[k >> 4] = r;
        }
    }
    if (writeTail && blockIdx.x == 0 && threadIdx.x == 0) outp[n] = E;
}

// ---------------------------------------------------------------------------
// Fused layer1+layer2 per 16-node tile (ndpk gather 4-batched). g stored fp8.
__global__ __launch_bounds__(256) void k_fused(
        const int* __restrict__ rowptr, const unsigned* __restrict__ sp2,
        const int2* __restrict__ ndpk, const float* __restrict__ dis,
        const short* __restrict__ T1T, const short* __restrict__ W2T,
        const float* __restrict__ b1, void* __restrict__ gq, int N) {
    __shared__ __align__(16) float wtile[16 * WP];
    __shared__ unsigned short otile[16 * OP];
    int tid = threadIdx.x;
    int v0 = blockIdx.x * 16;
    int nloc = min(16, N - v0);

    f32x4* w4 = (f32x4*)wtile;
    for (int i = tid; i < 16 * WP / 4; i += 256) {
        f32x4 z = {0.f, 0.f, 0.f, 0.f};
        w4[i] = z;
    }
    __syncthreads();

    if (tid < nloc) {                        // self loops
        int2 nd = ndpk[v0 + tid];
        atomicAdd(&wtile[tid * WP + nd.x], __int_as_float(nd.y));
    }
    int e0 = rowptr[v0], e1 = rowptr[min(v0 + 16, N)];
    for (int base = e0; base < e1; base += 1024) {
        unsigned sp[4];
        int2 nd[4];
#pragma unroll
        for (int j = 0; j < 4; ++j) {
            int i = base + tid + j * 256;
            sp[j] = (i < e1) ? sp2[i] : 0xffffffffu;
        }
#pragma unroll
        for (int j = 0; j < 4; ++j)
            if (sp[j] != 0xffffffffu) nd[j] = ndpk[sp[j] >> 4];
#pragma unroll
        for (int j = 0; j < 4; ++j)
            if (sp[j] != 0xffffffffu)
                atomicAdd(&wtile[(sp[j] & 15u) * WP + nd[j].x],
                          __int_as_float(nd[j].y));
    }
    __syncthreads();

    int wid = tid >> 6, lane = tid & 63;
    int m = lane & 15, g4 = lane >> 4;

    short8 a[4];
#pragma unroll
    for (int s = 0; s < 4; ++s) {
        float av[8];
        *(f32x4*)(av)     = *(const f32x4*)&wtile[m * WP + g4 * 8 + s * 32];
        *(f32x4*)(av + 4) = *(const f32x4*)&wtile[m * WP + g4 * 8 + s * 32 + 4];
        short8 f;
#pragma unroll
        for (int i = 0; i < 8; ++i) f[i] = f2bf(av[i]);
        a[s] = f;
    }
    float dvals[4];
#pragma unroll
    for (int r = 0; r < 4; ++r) {
        int v = v0 + g4 * 4 + r;
        dvals[r] = (v < N) ? dis[v] : 0.f;
    }

#pragma unroll
    for (int t = 0; t < 2; ++t) {
        int nt = wid * 2 + t;
        f32x4 acc = {0.f, 0.f, 0.f, 0.f};
        const short8* bp = (const short8*)(T1T + (size_t)(nt * 16 + m) * 128 + g4 * 8);
#pragma unroll
        for (int s = 0; s < 4; ++s)
            acc = __builtin_amdgcn_mfma_f32_16x16x32_bf16(a[s], bp[s * 4], acc, 0, 0, 0);
        int col = nt * 16 + m;
        float bb = b1[col];
#pragma unroll
        for (int r = 0; r < 4; ++r) {
            int row = g4 * 4 + r;
            otile[row * OP + col] =
                (unsigned short)f2bf(fmaxf(dvals[r] * acc[r] + bb, 0.f));
        }
    }
    __syncthreads();

    short8 a2[4];
#pragma unroll
    for (int s = 0; s < 4; ++s)
        a2[s] = *(const short8*)&otile[m * OP + g4 * 8 + s * 32];
    {
        int nt2 = wid;
        f32x4 acc = {0.f, 0.f, 0.f, 0.f};
        const short8* bp = (const short8*)(W2T + (size_t)(nt2 * 16 + m) * 128 + g4 * 8);
#pragma unroll
        for (int s = 0; s < 4; ++s)
            acc = __builtin_amdgcn_mfma_f32_16x16x32_bf16(a2[s], bp[s * 4], acc, 0, 0, 0);
#pragma unroll
        for (int r = 0; r < 4; ++r) {
            int row = g4 * 4 + r;
            if (row < nloc) {
                float val = dvals[r] * acc[r];
                size_t off = (size_t)(v0 + row) * 64 + nt2 * 16 + m;
#if GFP8
                int pk = __builtin_amdgcn_cvt_pk_fp8_f32(val, val, 0, false);
                ((unsigned char*)gq)[off] = (unsigned char)pk;
#else
                ((unsigned short*)gq)[off] = (unsigned short)f2bf(val);
#endif
            }
        }
    }
}

// ---------------------------------------------------------------------------
// Gather + relu + POOL per 16-node tile. g rows fp8 (64B).
__global__ __launch_bounds__(256) void k_gather3(
        const unsigned* __restrict__ sp2, const int* __restrict__ rowptr,
        const void* __restrict__ gq, const float* __restrict__ dis,
        const float* __restrict__ b2, const int* __restrict__ batch,
        float* __restrict__ pooled, int N) {
    __shared__ int lbuf[GCAP];
    __shared__ int lrp[17];
    __shared__ int ncur[16];
    __shared__ int sb[16];
    __shared__ float xt[16][64];
    int tid = threadIdx.x;
    int v0 = blockIdx.x * 16;
    int nloc = min(16, N - v0);
    if (tid < 17) lrp[tid] = rowptr[min(v0 + tid, N)];
    if (tid >= 32 && tid < 48) {
        int r = tid - 32;
        sb[r] = batch[min(v0 + r, N - 1)];
    }
    __syncthreads();
    int e0 = lrp[0], e1 = lrp[nloc];
    int span = e1 - e0;
    bool fits = (span <= GCAP);

    if (fits) {
        if (tid < 16) ncur[tid] = lrp[tid] - e0;
        __syncthreads();
        for (int i = e0 + tid; i < e1; i += 256) {
            unsigned sp = sp2[i];
            int old = atomicAdd(&ncur[sp & 15u], 1);
            lbuf[old] = (int)(sp >> 4);
        }
        __syncthreads();
    }

    int q = tid >> 4, l = tid & 15;
    if (q < nloc) {
        int v = v0 + q;
        f32x4 acc = {0.f, 0.f, 0.f, 0.f};
#if GFP8
        const unsigned* g32 = (const unsigned*)gq;      // row = 16 uints (64B)
        {
            unsigned u = g32[(size_t)v * 16 + l];        // self loop
            f32x2 lo = __builtin_amdgcn_cvt_pk_f32_fp8((int)u, false);
            f32x2 hi = __builtin_amdgcn_cvt_pk_f32_fp8((int)u, true);
            acc[0] = lo[0]; acc[1] = lo[1]; acc[2] = hi[0]; acc[3] = hi[1];
        }
        if (fits) {
            int e = lrp[q] - e0, re = lrp[q + 1] - e0;
            while (e < re) {
                int cnt = re - e;
                unsigned u[8];
#pragma unroll
                for (int j = 0; j < 8; ++j) {
                    int s = lbuf[min(e + j, re - 1)];
                    u[j] = g32[(size_t)s * 16 + l];
                }
#pragma unroll
                for (int j = 0; j < 8; ++j) {
                    float mask = (j < cnt) ? 1.f : 0.f;
                    f32x2 lo = __builtin_amdgcn_cvt_pk_f32_fp8((int)u[j], false);
                    f32x2 hi = __builtin_amdgcn_cvt_pk_f32_fp8((int)u[j], true);
                    acc[0] += mask * lo[0];
                    acc[1] += mask * lo[1];
                    acc[2] += mask * hi[0];
                    acc[3] += mask * hi[1];
                }
                e += 8;
            }
        } else {
            for (int i = e0; i < e1; ++i) {
                unsigned sp = sp2[i];
                if ((int)(sp & 15u) == q) {
                    unsigned u = g32[(size_t)(sp >> 4) * 16 + l];
                    f32x2 lo = __builtin_amdgcn_cvt_pk_f32_fp8((int)u, false);
                    f32x2 hi = __builtin_amdgcn_cvt_pk_f32_fp8((int)u, true);
                    acc[0] += lo[0]; acc[1] += lo[1];
                    acc[2] += hi[0]; acc[3] += hi[1];
                }
            }
        }
#else
        const uint2* g64 = (const uint2*)gq;             // row = 16 uint2 (128B)
        {
            uint2 su = g64[(size_t)v * 16 + l];          // self loop
            acc[0] = __uint_as_float(su.x << 16);
            acc[1] = __uint_as_float(su.x & 0xffff0000u);
            acc[2] = __uint_as_float(su.y << 16);
            acc[3] = __uint_as_float(su.y & 0xffff0000u);
        }
        if (fits) {
            int e = lrp[q] - e0, re = lrp[q + 1] - e0;
            while (e < re) {
                int cnt = re - e;
                uint2 u[8];
#pragma unroll
                for (int j = 0; j < 8; ++j) {
                    int s = lbuf[min(e + j, re - 1)];
                    u[j] = g64[(size_t)s * 16 + l];
                }
#pragma unroll
                for (int j = 0; j < 8; ++j) {
                    float mask = (j < cnt) ? 1.f : 0.f;
                    acc[0] += mask * __uint_as_float(u[j].x << 16);
                    acc[1] += mask * __uint_as_float(u[j].x & 0xffff0000u);
                    acc[2] += mask * __uint_as_float(u[j].y << 16);
                    acc[3] += mask * __uint_as_float(u[j].y & 0xffff0000u);
                }
                e += 8;
            }
        } else {
            for (int i = e0; i < e1; ++i) {
                unsigned sp = sp2[i];
                if ((int)(sp & 15u) == q) {
                    uint2 u = g64[(size_t)(sp >> 4) * 16 + l];
                    acc[0] += __uint_as_float(u.x << 16);
                    acc[1] += __uint_as_float(u.x & 0xffff0000u);
                    acc[2] += __uint_as_float(u.y << 16);
                    acc[3] += __uint_as_float(u.y & 0xffff0000u);
                }
            }
        }
#endif
        float dv = dis[v];
        f32x4 bb = *(const f32x4*)(b2 + l * 4);
#pragma unroll
        for (int j = 0; j < 4; ++j)
            xt[q][l * 4 + j] = fmaxf(dv * acc[j] + bb[j], 0.f);
    }
    __syncthreads();

    // segment-reduce rows by graph id, one atomic per segment x feature
    if (tid < 64) {
        float acc = 0.f;
        int bprev = sb[0];
        for (int r = 0; r < nloc; ++r) {
            int b = sb[r];
            if (b != bprev) {
                atomicAdd(&pooled[(size_t)bprev * 64 + tid], acc);
                acc = 0.f;
                bprev = b;
            }
            acc += xt[r][tid];
        }
        atomicAdd(&pooled[(size_t)bprev * 64 + tid], acc);
    }
}

// ---------------------------------------------------------------------------
// Head: one wave per graph. Bounds via binary search on sorted batch.
__device__ __forceinline__ int lower_bound(const int* __restrict__ a, int n, int key) {
    int lo = 0, hi = n;
    while (lo < hi) {
        int mid = (lo + hi) >> 1;
        if (a[mid] < key) lo = mid + 1; else hi = mid;
    }
    return lo;
}

__global__ void k_head(const float* __restrict__ pooled, const int* __restrict__ batch,
                       const float* __restrict__ fc_w, const float* __restrict__ fc_b,
                       float* __restrict__ out, int N, int ngraphs) {
    int gi = (blockIdx.x * 256 + threadIdx.x) >> 6;
    int lane = threadIdx.x & 63;
    if (gi >= ngraphs) return;
    int s = lower_bound(batch, N, gi);
    int e = lower_bound(batch, N, gi + 1);
    float c = fmaxf((float)(e - s), 1.0f);
    float a = (pooled[(size_t)gi * 64 + lane] / c) * fc_w[lane];
#pragma unroll
    for (int off = 32; off >= 1; off >>= 1) a += __shfl_down(a, off);
    if (lane == 0) out[gi] = 1.0f / (1.0f + expf(-(a + fc_b[0])));
}

extern "C" void kernel_launch(void* const* d_in, const int* in_sizes, int n_in,
                              void* d_out, int out_size, void* d_ws, size_t ws_size,
                              hipStream_t stream) {
    const int*   nid   = (const int*)d_in[0];
    const int*   eidx  = (const int*)d_in[1];
    const int*   batch = (const int*)d_in[2];
    const float* emb   = (const float*)d_in[3];
    const float* W1    = (const float*)d_in[4];
    const float* b1    = (const float*)d_in[5];
    const float* W2    = (const float*)d_in[6];
    const float* b2    = (const float*)d_in[7];
    const float* fcw   = (const float*)d_in[8];
    const float* fcb   = (const float*)d_in[9];

    const int N = in_sizes[0];
    const int E = in_sizes[1] / 2;
    const int G = out_size;
    const int T = (N + 15) / 16;
    const int* src = eidx;
    const int* dst = eidx + E;

    char* p = (char*)d_ws;
    auto alloc = [&](size_t bytes) {
        char* r = p;
        p += (bytes + 255) & ~(size_t)255;
        return r;
    };
    const int PBLK = 2048;
    const int CAP  = E / 8 + E / 32 + 4096;   // padded bucket capacity
    int*      degi2  = (int*)     alloc((size_t)N * 2 * 4);
    float*    dis    = (float*)   alloc((size_t)N * 4);
    int2*     ndpk   = (int2*)    alloc((size_t)N * 8);
    short*    T1T    = (short*)   alloc(128 * 128 * 2);
    short*    W2T    = (short*)   alloc(64 * 128 * 2);
    int*      rowptr = (int*)     alloc((size_t)(N + 1) * 4);
    int*      csums  = (int*)     alloc(4096 * 4);
    int*      bcur   = (int*)     alloc(8 * 16 * 4);
    int*      tcur   = (int*)     alloc((size_t)(T + 1) * 4);
    unsigned* sp1    = (unsigned*)alloc((size_t)8 * CAP * 4);
    unsigned* sp2    = (unsigned*)alloc((size_t)E * 4);
    void*     g      = (void*)    alloc((size_t)N * 64 * 2);  // fits bf16 or fp8
    float*    pooled = (float*)   alloc((size_t)G * 64 * 4);

    hipMemsetAsync(pooled, 0, (size_t)G * 64 * 4, stream);
    hipMemsetAsync(bcur, 0, 8 * 16 * 4, stream);

    // Partition (count+reserve+scatter in one kernel) + weight tables
    k_part_tabs<<<PBLK + 96, 256, 0, stream>>>(src, dst, bcur, sp1,
                                               emb, W1, W2, T1T, W2T,
                                               E, N, PBLK, CAP);

    // Degree histogram (zero global atomics)
    k_deg3<<<8 * DG_SUB * 2, 1024, 0, stream>>>(sp1, bcur, degi2, N, CAP);

    // deg -> rowptr + dis + ndpk (+ tcur side output in scan_c)
    int nch = (N + 1023) / 1024;
    k_scan_a<<<nch, 256, 0, stream>>>(degi2, degi2 + N, rowptr, csums,
                                      dis, nid, ndpk, N);
    k_scan_b<<<1, 256, 0, stream>>>(csums, nch);
    k_scan_c<<<nch, 256, 0, stream>>>(rowptr, csums, N, E, 1, tcur);

    // Tile grouping
    k_scat2<<<2048, 256, 0, stream>>>(sp1, bcur, tcur, sp2, N, CAP);

    k_fused<<<T, 256, 0, stream>>>(rowptr, sp2, ndpk, dis, T1T, W2T, b1, g, N);

    k_gather3<<<T, 256, 0, stream>>>(sp2, rowptr, g, dis, b2, batch, pooled, N);

    k_head<<<((long long)G * 64 + 255) / 256, 256, 0, stream>>>(
        pooled, batch, fcw, fcb, (float*)d_out, N, G);
}

// Round 24
// 166.622 us; speedup vs baseline: 1.2029x; 1.2029x over previous
//
#include <hip/hip_runtime.h>
#include <math.h>

typedef short short8 __attribute__((ext_vector_type(8)));
typedef float f32x4 __attribute__((ext_vector_type(4)));
typedef float f32x2 __attribute__((ext_vector_type(2)));

#define WP 132    // wtile pitch (f32)
#define OP 136    // otile pitch (bf16)
#define SC_C 8192 // k_scat2 chunk (edges)
#define SC_NB 832 // k_scat2 max tile-bins per bucket (<=783 for N=100000)
#define GCAP 1024 // k_gather3 LDS pair capacity
#define DG_SUB 16 // k_deg3 node-subranges per bucket
#define DG_LCAP 1024 // >= ceil(ceil(131072/8)/16); packing bounds N<=131072

// fp8 (e4m3) storage for the g table via gfx950 HW cvt; bf16 fallback.
#if defined(__has_builtin)
#if __has_builtin(__builtin_amdgcn_cvt_pk_f32_fp8) && \
    __has_builtin(__builtin_amdgcn_cvt_pk_fp8_f32)
#define GFP8 1
#endif
#endif
#ifndef GFP8
#define GFP8 0
#endif

// Packing (valid for N <= 131072): sp1 = (src<<14) | (d - bucket_lo),
// sp2 = (src<<4) | (d & 15).  sp2 is grouped by 16-node tile.

__device__ __forceinline__ short f2bf(float x) {
    unsigned u = __float_as_uint(x);
    u += 0x7fffu + ((u >> 16) & 1u);
    return (short)(u >> 16);
}

// ---------------------------------------------------------------------------
// Phase 1: per-wave bucket counts (ballot, no barriers, NO atomics).
// Blocks >= PBLK do the (independent) weight-table transform instead.
__global__ void k_cnt_tabs(const int* __restrict__ dst, int* __restrict__ wcnt,
                           const float* __restrict__ emb,
                           const float* __restrict__ W1,
                           const float* __restrict__ W2,
                           short* __restrict__ T1T, short* __restrict__ W2T,
                           int E, int N, int PBLK) {
    if (blockIdx.x >= PBLK) {                  // tabs part (block-uniform branch)
        int id = (blockIdx.x - PBLK) * 256 + threadIdx.x;
        if (id < 128 * 128) {
            int f = id >> 7, c = id & 127;
            float acc = 0.f;
#pragma unroll
            for (int k = 0; k < 64; ++k) acc += emb[c * 64 + k] * W1[k * 128 + f];
            T1T[id] = f2bf(acc);
        } else {
            int id2 = id - 128 * 128;
            if (id2 < 64 * 128) {
                int f = id2 >> 7, k = id2 & 127;
                W2T[id2] = f2bf(W2[k * 64 + f]);
            }
        }
        return;
    }
    int lane = threadIdx.x & 63;
    int gw = blockIdx.x * 4 + (threadIdx.x >> 6);
    int TOT = PBLK * 4;
    int cnt[8] = {0, 0, 0, 0, 0, 0, 0, 0};
    for (long long base = (long long)gw * 64; base < E; base += (long long)TOT * 64) {
        int i = (int)base + lane;
        bool valid = (i < E);
        int d = valid ? dst[i] : 0;
        int b = valid ? (int)(((long long)d * 8) / N) : -1;
#pragma unroll
        for (int k = 0; k < 8; ++k)
            cnt[k] += (int)__popcll(__ballot(b == k));
    }
#pragma unroll
    for (int k = 0; k < 8; ++k)
        if (lane == 0) wcnt[k * TOT + gw] = cnt[k];   // bucket-major
}

// Phase 2: scatter packed pairs into per-wave private regions (no atomics).
__global__ void k_scat(const int* __restrict__ src, const int* __restrict__ dst,
                       const int* __restrict__ wscan, unsigned* __restrict__ sp1,
                       int E, int N) {
    int lane = threadIdx.x & 63;
    int gw = blockIdx.x * 4 + (threadIdx.x >> 6);
    int TOT = gridDim.x * 4;
    int cur[8];
#pragma unroll
    for (int k = 0; k < 8; ++k) cur[k] = wscan[k * TOT + gw];
    for (long long base = (long long)gw * 64; base < E; base += (long long)TOT * 64) {
        int i = (int)base + lane;
        bool valid = (i < E);
        int d = 0, s = 0;
        if (valid) { d = dst[i]; s = src[i]; }
        int b = valid ? (int)(((long long)d * 8) / N) : -1;
        unsigned packed = 0;
        if (valid) {
            int lo = (int)((long long)N * b / 8);
            packed = ((unsigned)s << 14) | (unsigned)(d - lo);
        }
#pragma unroll
        for (int k = 0; k < 8; ++k) {
            unsigned long long mk = __ballot(b == k);
            if (b == k) {
                int pref = (int)__popcll(mk & ((1ull << lane) - 1ull));
                sp1[cur[k] + pref] = packed;
            }
            cur[k] += (int)__popcll(mk);
        }
    }
}

// Degree histogram with ZERO global atomics (8 buckets x 16 subranges x 2
// halves; LDS histogram + plain coalesced stores; scan sums the halves).
__global__ __launch_bounds__(1024) void k_deg3(
        const unsigned* __restrict__ sp1, const int* __restrict__ wscan,
        int* __restrict__ degi2, int E, int N, int TOTW) {
    __shared__ int h[DG_LCAP];
    int b   = blockIdx.x & 7;
    int hf  = (blockIdx.x >> 3) & 1;
    int sb  = blockIdx.x >> 4;
    int tid = threadIdx.x;
    int lo = (int)((long long)N * b / 8);
    int hi = (int)((long long)N * (b + 1) / 8);
    int range = hi - lo;
    int sub = (range + DG_SUB - 1) / DG_SUB;
    int nlo = sb * sub;
    int nhi = min(nlo + sub, range);
    int cnt = nhi - nlo;
    if (cnt <= 0) return;                      // uniform across block
    for (int i = tid; i < cnt; i += 1024) h[i] = 0;
    __syncthreads();
    int beg = wscan[b * TOTW];
    int end = (b < 7) ? wscan[(b + 1) * TOTW] : E;
    int span = end - beg;
    int hb = beg + hf * (span >> 1);
    int he = (hf == 0) ? (beg + (span >> 1)) : end;
    for (int i = hb + tid; i < he; i += 1024) {
        int dl = (int)(sp1[i] & 16383u) - nlo;
        if ((unsigned)dl < (unsigned)cnt) atomicAdd(&h[dl], 1);
    }
    __syncthreads();
    int* dout = degi2 + (size_t)hf * N + lo + nlo;
    for (int i = tid; i < cnt; i += 1024) dout[i] = h[i];
}

// Phase 3: bucket -> 16-node-tile groups with LDS-staged COALESCED writes.
__global__ __launch_bounds__(256) void k_scat2(
        const unsigned* __restrict__ sp1, const int* __restrict__ wscan,
        int* __restrict__ tcur, unsigned* __restrict__ sp2,
        int E, int N, int TOTW) {
    __shared__ unsigned staged[SC_C];
    __shared__ int hist[SC_NB], hstart[SC_NB], hoff[SC_NB], gbase[SC_NB];
    __shared__ int sdata[256];
    int b = blockIdx.x & 7;
    int nb = gridDim.x >> 3, bi = blockIdx.x >> 3;
    int lo = (int)((long long)N * b / 8);
    int t0 = lo >> 4;
    int beg = wscan[b * TOTW];
    int end = (b < 7) ? wscan[(b + 1) * TOTW] : E;
    int tid = threadIdx.x;

    for (int cb = beg + bi * SC_C; cb < end; cb += nb * SC_C) {
        int count = min(SC_C, end - cb);
        for (int j = tid; j < SC_NB; j += 256) hist[j] = 0;
        __syncthreads();

        unsigned v[SC_C / 256];
#pragma unroll
        for (int j = 0; j < SC_C / 256; ++j) {
            int i = j * 256 + tid;
            v[j] = 0;
            if (i < count) {
                unsigned sp = sp1[cb + i];
                v[j] = sp;
                int d = (int)(sp & 16383u) + lo;
                atomicAdd(&hist[(d >> 4) - t0], 1);
            }
        }
        __syncthreads();

        int loc[4]; int lsum = 0;
#pragma unroll
        for (int j = 0; j < 4; ++j) {
            int idx = tid * 4 + j;
            loc[j] = (idx < SC_NB) ? hist[idx] : 0;
            lsum += loc[j];
        }
        sdata[tid] = lsum;
        __syncthreads();
        for (int off = 1; off < 256; off <<= 1) {
            int add = (tid >= off) ? sdata[tid - off] : 0;
            __syncthreads();
            sdata[tid] += add;
            __syncthreads();
        }
        int excl = sdata[tid] - lsum;
        int run = 0;
#pragma unroll
        for (int j = 0; j < 4; ++j) {
            int idx = tid * 4 + j;
            if (idx < SC_NB) { hstart[idx] = excl + run; hoff[idx] = excl + run; }
            run += loc[j];
        }
        __syncthreads();

        for (int j = tid; j < SC_NB; j += 256)
            if (hist[j] > 0) gbase[j] = atomicAdd(&tcur[t0 + j], hist[j]);
#pragma unroll
        for (int j = 0; j < SC_C / 256; ++j) {
            int i = j * 256 + tid;
            if (i < count) {
                int d = (int)(v[j] & 16383u) + lo;
                int bin = (d >> 4) - t0;
                int old = atomicAdd(&hoff[bin], 1);
                staged[old] = v[j];
            }
        }
        __syncthreads();

        for (int i = tid; i < count; i += 256) {
            unsigned sp = staged[i];
            int d = (int)(sp & 16383u) + lo;
            int bin = (d >> 4) - t0;
            int pos = gbase[bin] + (i - hstart[bin]);
            unsigned s = sp >> 14;
            sp2[pos] = (s << 4) | (unsigned)(d & 15);
        }
        __syncthreads();
    }
}

// ---------------------------------------------------------------------------
// Exclusive scans. in2 optional (summed); dis/ndpk optional; tail optional.
__global__ void k_scan_a(const int* __restrict__ in, const int* __restrict__ in2,
                         int* __restrict__ outp, int* __restrict__ csums,
                         float* __restrict__ dis, const int* __restrict__ nid,
                         int2* __restrict__ ndpk, int n) {
    __shared__ int sdata[256];
    int tid = threadIdx.x;
    int idx = blockIdx.x * 1024 + tid * 4;
    int v[4];
#pragma unroll
    for (int j = 0; j < 4; ++j) {
        v[j] = 0;
        if (idx + j < n) {
            v[j] = in[idx + j];
            if (in2 != nullptr) v[j] += in2[idx + j];
            if (dis != nullptr) {
                float dv = rsqrtf((float)(v[j] + 1));
                dis[idx + j] = dv;
                int2 nd; nd.x = nid[idx + j]; nd.y = __float_as_int(dv);
                ndpk[idx + j] = nd;
            }
        }
    }
    int tsum = v[0] + v[1] + v[2] + v[3];
    sdata[tid] = tsum;
    __syncthreads();
    for (int off = 1; off < 256; off <<= 1) {
        int add = (tid >= off) ? sdata[tid - off] : 0;
        __syncthreads();
        sdata[tid] += add;
        __syncthreads();
    }
    int excl = sdata[tid] - tsum;
    int run = 0;
#pragma unroll
    for (int j = 0; j < 4; ++j) {
        if (idx + j < n) outp[idx + j] = excl + run;
        run += v[j];
    }
    if (tid == 255) csums[blockIdx.x] = sdata[255];
}

__global__ void k_scan_b(int* __restrict__ csums, int nch) {
    __shared__ int sdata[256];
    int tid = threadIdx.x;
    int v[4];
#pragma unroll
    for (int j = 0; j < 4; ++j) {
        int i = tid * 4 + j;
        v[j] = (i < nch) ? csums[i] : 0;
    }
    int tsum = v[0] + v[1] + v[2] + v[3];
    sdata[tid] = tsum;
    __syncthreads();
    for (int off = 1; off < 256; off <<= 1) {
        int add = (tid >= off) ? sdata[tid - off] : 0;
        __syncthreads();
        sdata[tid] += add;
        __syncthreads();
    }
    int excl = sdata[tid] - tsum;
    int run = 0;
#pragma unroll
    for (int j = 0; j < 4; ++j) {
        int i = tid * 4 + j;
        if (i < nch) csums[i] = excl + run;
        run += v[j];
    }
}

// scan_c: add chunk offsets; optional rowptr tail; optional tcur side-output.
__global__ void k_scan_c(int* __restrict__ outp, const int* __restrict__ csums,
                         int n, int E, int writeTail, int* __restrict__ tcur) {
    int idx = blockIdx.x * 1024 + threadIdx.x * 4;
    int add = csums[blockIdx.x];
#pragma unroll
    for (int j = 0; j < 4; ++j) {
        int k = idx + j;
        if (k < n) {
            int r = outp[k] + add;
            outp[k] = r;
            if (tcur != nullptr && (k & 15) == 0) tcur[k >> 4] = r;
        }
    }
    if (writeTail && blockIdx.x == 0 && threadIdx.x == 0) outp[n] = E;
}

// ---------------------------------------------------------------------------
// Fused layer1+layer2 per 16-node tile (ndpk gather 4-batched). g stored fp8.
__global__ __launch_bounds__(256) void k_fused(
        const int* __restrict__ rowptr, const unsigned* __restrict__ sp2,
        const int2* __restrict__ ndpk, const float* __restrict__ dis,
        const short* __restrict__ T1T, const short* __restrict__ W2T,
        const float* __restrict__ b1, void* __restrict__ gq, int N) {
    __shared__ __align__(16) float wtile[16 * WP];
    __shared__ unsigned short otile[16 * OP];
    int tid = threadIdx.x;
    int v0 = blockIdx.x * 16;
    int nloc = min(16, N - v0);

    f32x4* w4 = (f32x4*)wtile;
    for (int i = tid; i < 16 * WP / 4; i += 256) {
        f32x4 z = {0.f, 0.f, 0.f, 0.f};
        w4[i] = z;
    }
    __syncthreads();

    if (tid < nloc) {                        // self loops
        int2 nd = ndpk[v0 + tid];
        atomicAdd(&wtile[tid * WP + nd.x], __int_as_float(nd.y));
    }
    int e0 = rowptr[v0], e1 = rowptr[min(v0 + 16, N)];
    for (int base = e0; base < e1; base += 1024) {
        unsigned sp[4];
        int2 nd[4];
#pragma unroll
        for (int j = 0; j < 4; ++j) {
            int i = base + tid + j * 256;
            sp[j] = (i < e1) ? sp2[i] : 0xffffffffu;
        }
#pragma unroll
        for (int j = 0; j < 4; ++j)
            if (sp[j] != 0xffffffffu) nd[j] = ndpk[sp[j] >> 4];
#pragma unroll
        for (int j = 0; j < 4; ++j)
            if (sp[j] != 0xffffffffu)
                atomicAdd(&wtile[(sp[j] & 15u) * WP + nd[j].x],
                          __int_as_float(nd[j].y));
    }
    __syncthreads();

    int wid = tid >> 6, lane = tid & 63;
    int m = lane & 15, g4 = lane >> 4;

    short8 a[4];
#pragma unroll
    for (int s = 0; s < 4; ++s) {
        float av[8];
        *(f32x4*)(av)     = *(const f32x4*)&wtile[m * WP + g4 * 8 + s * 32];
        *(f32x4*)(av + 4) = *(const f32x4*)&wtile[m * WP + g4 * 8 + s * 32 + 4];
        short8 f;
#pragma unroll
        for (int i = 0; i < 8; ++i) f[i] = f2bf(av[i]);
        a[s] = f;
    }
    float dvals[4];
#pragma unroll
    for (int r = 0; r < 4; ++r) {
        int v = v0 + g4 * 4 + r;
        dvals[r] = (v < N) ? dis[v] : 0.f;
    }

#pragma unroll
    for (int t = 0; t < 2; ++t) {
        int nt = wid * 2 + t;
        f32x4 acc = {0.f, 0.f, 0.f, 0.f};
        const short8* bp = (const short8*)(T1T + (size_t)(nt * 16 + m) * 128 + g4 * 8);
#pragma unroll
        for (int s = 0; s < 4; ++s)
            acc = __builtin_amdgcn_mfma_f32_16x16x32_bf16(a[s], bp[s * 4], acc, 0, 0, 0);
        int col = nt * 16 + m;
        float bb = b1[col];
#pragma unroll
        for (int r = 0; r < 4; ++r) {
            int row = g4 * 4 + r;
            otile[row * OP + col] =
                (unsigned short)f2bf(fmaxf(dvals[r] * acc[r] + bb, 0.f));
        }
    }
    __syncthreads();

    short8 a2[4];
#pragma unroll
    for (int s = 0; s < 4; ++s)
        a2[s] = *(const short8*)&otile[m * OP + g4 * 8 + s * 32];
    {
        int nt2 = wid;
        f32x4 acc = {0.f, 0.f, 0.f, 0.f};
        const short8* bp = (const short8*)(W2T + (size_t)(nt2 * 16 + m) * 128 + g4 * 8);
#pragma unroll
        for (int s = 0; s < 4; ++s)
            acc = __builtin_amdgcn_mfma_f32_16x16x32_bf16(a2[s], bp[s * 4], acc, 0, 0, 0);
#pragma unroll
        for (int r = 0; r < 4; ++r) {
            int row = g4 * 4 + r;
            if (row < nloc) {
                float val = dvals[r] * acc[r];
                size_t off = (size_t)(v0 + row) * 64 + nt2 * 16 + m;
#if GFP8
                int pk = __builtin_amdgcn_cvt_pk_fp8_f32(val, val, 0, false);
                ((unsigned char*)gq)[off] = (unsigned char)pk;
#else
                ((unsigned short*)gq)[off] = (unsigned short)f2bf(val);
#endif
            }
        }
    }
}

// ---------------------------------------------------------------------------
// Gather + relu + POOL per 16-node tile. g rows fp8 (64B).
__global__ __launch_bounds__(256) void k_gather3(
        const unsigned* __restrict__ sp2, const int* __restrict__ rowptr,
        const void* __restrict__ gq, const float* __restrict__ dis,
        const float* __restrict__ b2, const int* __restrict__ batch,
        float* __restrict__ pooled, int N) {
    __shared__ int lbuf[GCAP];
    __shared__ int lrp[17];
    __shared__ int ncur[16];
    __shared__ int sb[16];
    __shared__ float xt[16][64];
    int tid = threadIdx.x;
    int v0 = blockIdx.x * 16;
    int nloc = min(16, N - v0);
    if (tid < 17) lrp[tid] = rowptr[min(v0 + tid, N)];
    if (tid >= 32 && tid < 48) {
        int r = tid - 32;
        sb[r] = batch[min(v0 + r, N - 1)];
    }
    __syncthreads();
    int e0 = lrp[0], e1 = lrp[nloc];
    int span = e1 - e0;
    bool fits = (span <= GCAP);

    if (fits) {
        if (tid < 16) ncur[tid] = lrp[tid] - e0;
        __syncthreads();
        for (int i = e0 + tid; i < e1; i += 256) {
            unsigned sp = sp2[i];
            int old = atomicAdd(&ncur[sp & 15u], 1);
            lbuf[old] = (int)(sp >> 4);
        }
        __syncthreads();
    }

    int q = tid >> 4, l = tid & 15;
    if (q < nloc) {
        int v = v0 + q;
        f32x4 acc = {0.f, 0.f, 0.f, 0.f};
#if GFP8
        const unsigned* g32 = (const unsigned*)gq;      // row = 16 uints (64B)
        {
            unsigned u = g32[(size_t)v * 16 + l];        // self loop
            f32x2 lo = __builtin_amdgcn_cvt_pk_f32_fp8((int)u, false);
            f32x2 hi = __builtin_amdgcn_cvt_pk_f32_fp8((int)u, true);
            acc[0] = lo[0]; acc[1] = lo[1]; acc[2] = hi[0]; acc[3] = hi[1];
        }
        if (fits) {
            int e = lrp[q] - e0, re = lrp[q + 1] - e0;
            while (e < re) {
                int cnt = re - e;
                unsigned u[8];
#pragma unroll
                for (int j = 0; j < 8; ++j) {
                    int s = lbuf[min(e + j, re - 1)];
                    u[j] = g32[(size_t)s * 16 + l];
                }
#pragma unroll
                for (int j = 0; j < 8; ++j) {
                    float mask = (j < cnt) ? 1.f : 0.f;
                    f32x2 lo = __builtin_amdgcn_cvt_pk_f32_fp8((int)u[j], false);
                    f32x2 hi = __builtin_amdgcn_cvt_pk_f32_fp8((int)u[j], true);
                    acc[0] += mask * lo[0];
                    acc[1] += mask * lo[1];
                    acc[2] += mask * hi[0];
                    acc[3] += mask * hi[1];
                }
                e += 8;
            }
        } else {
            for (int i = e0; i < e1; ++i) {
                unsigned sp = sp2[i];
                if ((int)(sp & 15u) == q) {
                    unsigned u = g32[(size_t)(sp >> 4) * 16 + l];
                    f32x2 lo = __builtin_amdgcn_cvt_pk_f32_fp8((int)u, false);
                    f32x2 hi = __builtin_amdgcn_cvt_pk_f32_fp8((int)u, true);
                    acc[0] += lo[0]; acc[1] += lo[1];
                    acc[2] += hi[0]; acc[3] += hi[1];
                }
            }
        }
#else
        const uint2* g64 = (const uint2*)gq;             // row = 16 uint2 (128B)
        {
            uint2 su = g64[(size_t)v * 16 + l];          // self loop
            acc[0] = __uint_as_float(su.x << 16);
            acc[1] = __uint_as_float(su.x & 0xffff0000u);
            acc[2] = __uint_as_float(su.y << 16);
            acc[3] = __uint_as_float(su.y & 0xffff0000u);
        }
        if (fits) {
            int e = lrp[q] - e0, re = lrp[q + 1] - e0;
            while (e < re) {
                int cnt = re - e;
                uint2 u[8];
#pragma unroll
                for (int j = 0; j < 8; ++j) {
                    int s = lbuf[min(e + j, re - 1)];
                    u[j] = g64[(size_t)s * 16 + l];
                }
#pragma unroll
                for (int j = 0; j < 8; ++j) {
                    float mask = (j < cnt) ? 1.f : 0.f;
                    acc[0] += mask * __uint_as_float(u[j].x << 16);
                    acc[1] += mask * __uint_as_float(u[j].x & 0xffff0000u);
                    acc[2] += mask * __uint_as_float(u[j].y << 16);
                    acc[3] += mask * __uint_as_float(u[j].y & 0xffff0000u);
                }
                e += 8;
            }
        } else {
            for (int i = e0; i < e1; ++i) {
                unsigned sp = sp2[i];
                if ((int)(sp & 15u) == q) {
                    uint2 u = g64[(size_t)(sp >> 4) * 16 + l];
                    acc[0] += __uint_as_float(u.x << 16);
                    acc[1] += __uint_as_float(u.x & 0xffff0000u);
                    acc[2] += __uint_as_float(u.y << 16);
                    acc[3] += __uint_as_float(u.y & 0xffff0000u);
                }
            }
        }
#endif
        float dv = dis[v];
        f32x4 bb = *(const f32x4*)(b2 + l * 4);
#pragma unroll
        for (int j = 0; j < 4; ++j)
            xt[q][l * 4 + j] = fmaxf(dv * acc[j] + bb[j], 0.f);
    }
    __syncthreads();

    // segment-reduce rows by graph id, one atomic per segment x feature
    if (tid < 64) {
        float acc = 0.f;
        int bprev = sb[0];
        for (int r = 0; r < nloc; ++r) {
            int b = sb[r];
            if (b != bprev) {
                atomicAdd(&pooled[(size_t)bprev * 64 + tid], acc);
                acc = 0.f;
                bprev = b;
            }
            acc += xt[r][tid];
        }
        atomicAdd(&pooled[(size_t)bprev * 64 + tid], acc);
    }
}

// ---------------------------------------------------------------------------
// Head: one wave per graph. Bounds via binary search on sorted batch.
__device__ __forceinline__ int lower_bound(const int* __restrict__ a, int n, int key) {
    int lo = 0, hi = n;
    while (lo < hi) {
        int mid = (lo + hi) >> 1;
        if (a[mid] < key) lo = mid + 1; else hi = mid;
    }
    return lo;
}

__global__ void k_head(const float* __restrict__ pooled, const int* __restrict__ batch,
                       const float* __restrict__ fc_w, const float* __restrict__ fc_b,
                       float* __restrict__ out, int N, int ngraphs) {
    int gi = (blockIdx.x * 256 + threadIdx.x) >> 6;
    int lane = threadIdx.x & 63;
    if (gi >= ngraphs) return;
    int s = lower_bound(batch, N, gi);
    int e = lower_bound(batch, N, gi + 1);
    float c = fmaxf((float)(e - s), 1.0f);
    float a = (pooled[(size_t)gi * 64 + lane] / c) * fc_w[lane];
#pragma unroll
    for (int off = 32; off >= 1; off >>= 1) a += __shfl_down(a, off);
    if (lane == 0) out[gi] = 1.0f / (1.0f + expf(-(a + fc_b[0])));
}

extern "C" void kernel_launch(void* const* d_in, const int* in_sizes, int n_in,
                              void* d_out, int out_size, void* d_ws, size_t ws_size,
                              hipStream_t stream) {
    const int*   nid   = (const int*)d_in[0];
    const int*   eidx  = (const int*)d_in[1];
    const int*   batch = (const int*)d_in[2];
    const float* emb   = (const float*)d_in[3];
    const float* W1    = (const float*)d_in[4];
    const float* b1    = (const float*)d_in[5];
    const float* W2    = (const float*)d_in[6];
    const float* b2    = (const float*)d_in[7];
    const float* fcw   = (const float*)d_in[8];
    const float* fcb   = (const float*)d_in[9];

    const int N = in_sizes[0];
    const int E = in_sizes[1] / 2;
    const int G = out_size;
    const int T = (N + 15) / 16;
    const int* src = eidx;
    const int* dst = eidx + E;

    char* p = (char*)d_ws;
    auto alloc = [&](size_t bytes) {
        char* r = p;
        p += (bytes + 255) & ~(size_t)255;
        return r;
    };
    const int PBLK = 2048;
    const int TOTW = PBLK * 4;
    const int NW   = 8 * TOTW;
    int*      degi2  = (int*)     alloc((size_t)N * 2 * 4);
    float*    dis    = (float*)   alloc((size_t)N * 4);
    int2*     ndpk   = (int2*)    alloc((size_t)N * 8);
    short*    T1T    = (short*)   alloc(128 * 128 * 2);
    short*    W2T    = (short*)   alloc(64 * 128 * 2);
    int*      rowptr = (int*)     alloc((size_t)(N + 1) * 4);
    int*      csums  = (int*)     alloc(4096 * 4);
    int*      wcnt   = (int*)     alloc((size_t)NW * 4);
    int*      wscan  = (int*)     alloc((size_t)(NW + 1) * 4);
    int*      csums2 = (int*)     alloc(256 * 4);
    int*      tcur   = (int*)     alloc((size_t)(T + 1) * 4);
    unsigned* sp1    = (unsigned*)alloc((size_t)E * 4);
    unsigned* sp2    = (unsigned*)alloc((size_t)E * 4);
    void*     g      = (void*)    alloc((size_t)N * 64 * 2);  // fits bf16 or fp8
    float*    pooled = (float*)   alloc((size_t)G * 64 * 4);

    hipMemsetAsync(pooled, 0, (size_t)G * 64 * 4, stream);

    // Phase 1: bucket counts (no atomics) + weight tables (folded dispatch)
    k_cnt_tabs<<<PBLK + 96, 256, 0, stream>>>(dst, wcnt, emb, W1, W2, T1T, W2T,
                                              E, N, PBLK);

    // wcnt -> wscan
    int nch2 = (NW + 1023) / 1024;
    k_scan_a<<<nch2, 256, 0, stream>>>(wcnt, nullptr, wscan, csums2,
                                       nullptr, nullptr, nullptr, NW);
    k_scan_b<<<1, 256, 0, stream>>>(csums2, nch2);
    k_scan_c<<<nch2, 256, 0, stream>>>(wscan, csums2, NW, 0, 0, nullptr);

    // Phase 2: packed bucket scatter; degree histogram (zero global atomics)
    k_scat<<<PBLK, 256, 0, stream>>>(src, dst, wscan, sp1, E, N);
    k_deg3<<<8 * DG_SUB * 2, 1024, 0, stream>>>(sp1, wscan, degi2, E, N, TOTW);

    // deg -> rowptr + dis + ndpk (+ tcur side output in scan_c)
    int nch = (N + 1023) / 1024;
    k_scan_a<<<nch, 256, 0, stream>>>(degi2, degi2 + N, rowptr, csums,
                                      dis, nid, ndpk, N);
    k_scan_b<<<1, 256, 0, stream>>>(csums, nch);
    k_scan_c<<<nch, 256, 0, stream>>>(rowptr, csums, N, E, 1, tcur);

    // Phase 3: tile grouping
    k_scat2<<<2048, 256, 0, stream>>>(sp1, wscan, tcur, sp2, E, N, TOTW);

    k_fused<<<T, 256, 0, stream>>>(rowptr, sp2, ndpk, dis, T1T, W2T, b1, g, N);

    k_gather3<<<T, 256, 0, stream>>>(sp2, rowptr, g, dis, b2, batch, pooled, N);

    k_head<<<((long long)G * 64 + 255) / 256, 256, 0, stream>>>(
        pooled, batch, fcw, fcb, (float*)d_out, N, G);
}